// Round 1
// baseline (15770.508 us; speedup 1.0000x reference)
//
#include <hip/hip_runtime.h>
#include <cstdint>
#include <cstddef>

typedef _Float16 half_t;
typedef _Float16 half2_t __attribute__((ext_vector_type(2)));
typedef _Float16 half8_t __attribute__((ext_vector_type(8)));
typedef float   float4_t __attribute__((ext_vector_type(4)));

#define L_N 2
#define B_N 32
#define S_N 2048
#define H_N 256
#define G_N 1024            // 4H
#define M_N (B_N*S_N)       // 65536

// recurrent kernel: K split between VGPR-resident and LDS-resident weights (fp16 pairs)
#define KREG 96             // pairs (=192 k values) per gate in VGPRs
#define KLDS 32             // pairs (=64 k values) per gate in LDS
#define SMEM_BYTES (KLDS*256*16 + 2*128*4)   // 128KB weights + double-buffered h

// ws layout (bytes)
#define WS_A0   0ull                 // fp16 [M][H]: layer-0 A; later reused as h0 sequence
#define WS_XP   33554432ull          // fp16 [M][G]: input projection (bias folded)
#define WS_WI   167772160ull         // fp16 [L][G][H]
#define WS_WH   168820736ull         // fp16 [L][G][H]
#define WS_BSUM 169869312ull         // f32 [L][G]  (b_ih + b_hh)

__global__ void cvt_f32_f16(const float* __restrict__ in, half_t* __restrict__ out, int n){
  int i = blockIdx.x*256 + threadIdx.x;
  if (i < n) out[i] = (half_t)in[i];
}

__global__ void make_bsum(const float* __restrict__ bi, const float* __restrict__ bh,
                          float* __restrict__ bs, int n){
  int i = blockIdx.x*256 + threadIdx.x;
  if (i < n) bs[i] = bi[i] + bh[i];
}

// XP[m,g] = sum_k A[m,k] * W[g,k] + bsum[g]; A:[M][256] fp16, W:[1024][256] fp16
// block = 256 thr = 4 waves; block tile 64(M) x 64(N); wave = 16(M) x 64(N)
__global__ __launch_bounds__(256) void gemm_xp(
    const half_t* __restrict__ A, const half_t* __restrict__ W,
    const float* __restrict__ bsum, half_t* __restrict__ XP)
{
  const int wave = threadIdx.x >> 6;
  const int lane = threadIdx.x & 63;
  const int l15 = lane & 15, quad = lane >> 4;
  const int m0 = blockIdx.x*64 + wave*16;
  const int n0 = blockIdx.y*64;
  float4_t acc[4] = {{0,0,0,0},{0,0,0,0},{0,0,0,0},{0,0,0,0}};
  const half_t* arow = A + (size_t)(m0 + l15)*H_N + quad*8;
  const half_t* brow[4];
  #pragma unroll
  for (int nt=0; nt<4; ++nt)
    brow[nt] = W + (size_t)(n0 + nt*16 + l15)*H_N + quad*8;
  #pragma unroll
  for (int k0=0; k0<H_N; k0+=32){
    half8_t af = *(const half8_t*)(arow + k0);
    #pragma unroll
    for (int nt=0; nt<4; ++nt){
      half8_t bf = *(const half8_t*)(brow[nt] + k0);
      acc[nt] = __builtin_amdgcn_mfma_f32_16x16x32_f16(af, bf, acc[nt], 0, 0, 0);
    }
  }
  #pragma unroll
  for (int nt=0; nt<4; ++nt){
    const int col = n0 + nt*16 + l15;         // C/D: col = lane&15
    const float bs = bsum[col];
    #pragma unroll
    for (int r=0; r<4; ++r){                  // row = quad*4 + r
      XP[(size_t)(m0 + quad*4 + r)*G_N + col] = (half_t)(acc[nt][r] + bs);
    }
  }
}

__device__ __forceinline__ float sigf(float x){ return 1.f/(1.f + __expf(-x)); }
__device__ __forceinline__ float tanh_f(float x){ return 1.f - 2.f/(__expf(2.f*x) + 1.f); }

// Persistent per-batch-chain LSTM recurrence. 1 block = 1 chain = 1 CU.
// thread j owns gates {j, j+256, j+512, j+768} -> updates c_j, h_j with no gate exchange.
// h double-buffered in LDS (broadcast reads); weights: KREG pairs in VGPRs + KLDS pairs in LDS.
__global__ __launch_bounds__(256,1) void lstm_rec(
    const uint32_t* __restrict__ Wp,   // fp16-pair view of Wh [1024][128]
    const half_t*  __restrict__ xp,    // [M][1024], biases folded
    half_t* __restrict__ h16,          // layer-0 h sequence out (fp16) or unused
    float*  __restrict__ h32,          // layer-1 h sequence out (fp32, = d_out x) or unused
    float*  __restrict__ hT, float* __restrict__ cT, int wr32)
{
  extern __shared__ unsigned char smem[];
  uint4*    wlds = (uint4*)smem;                              // [KLDS][256]
  uint32_t* hbuf = (uint32_t*)(smem + (size_t)KLDS*256*16);   // [2][128] h pairs
  const int j = threadIdx.x;
  const int b = blockIdx.x;

  // --- load VGPR-resident weights (k pairs 0..KREG-1 of each of 4 gate rows)
  uint32_t wreg[4][KREG];
  #pragma unroll
  for (int q=0; q<4; ++q){
    const uint32_t* wp = Wp + (size_t)(q*256 + j)*128;
    #pragma unroll
    for (int k=0; k<KREG; ++k) wreg[q][k] = wp[k];
  }
  // --- stage LDS-resident weights (pairs KREG..127), packed 4-gates per uint4
  {
    const uint32_t* w0 = Wp + (size_t)(  0 + j)*128 + KREG;
    const uint32_t* w1 = Wp + (size_t)(256 + j)*128 + KREG;
    const uint32_t* w2 = Wp + (size_t)(512 + j)*128 + KREG;
    const uint32_t* w3 = Wp + (size_t)(768 + j)*128 + KREG;
    #pragma unroll
    for (int k=0; k<KLDS; ++k){
      uint4 v; v.x = w0[k]; v.y = w1[k]; v.z = w2[k]; v.w = w3[k];
      wlds[k*256 + j] = v;
    }
  }
  if (j < 128) hbuf[128 + j] = 0u;   // initial h (buffer 1) = 0
  float c = 0.f;
  __syncthreads();

  const size_t base = (size_t)b * S_N;
  for (int t=0; t<S_N; ++t){
    const half_t* xr = xp + (base + t)*G_N + j;
    const half_t x0 = xr[0], x1 = xr[256], x2 = xr[512], x3 = xr[768];
    const uint32_t* hr = hbuf + ((t+1)&1)*128;   // read prev-step h
    float a0=0.f, a1=0.f, a2=0.f, a3=0.f;

    // VGPR-weight section: 3 blocks of 32 pairs, fp16 pk-fma, f32 flush per block
    #pragma unroll
    for (int blk=0; blk<3; ++blk){
      half2_t s0 = {(_Float16)0.f,(_Float16)0.f}, s1 = s0, s2 = s0, s3 = s0;
      #pragma unroll
      for (int k8=0; k8<8; ++k8){
        const uint4 hh = *(const uint4*)(hr + blk*32 + k8*4);
        #pragma unroll
        for (int p=0; p<4; ++p){
          const int k = blk*32 + k8*4 + p;
          const half2_t h2 = __builtin_bit_cast(half2_t, (&hh.x)[p]);
          s0 = __builtin_elementwise_fma(__builtin_bit_cast(half2_t, wreg[0][k]), h2, s0);
          s1 = __builtin_elementwise_fma(__builtin_bit_cast(half2_t, wreg[1][k]), h2, s1);
          s2 = __builtin_elementwise_fma(__builtin_bit_cast(half2_t, wreg[2][k]), h2, s2);
          s3 = __builtin_elementwise_fma(__builtin_bit_cast(half2_t, wreg[3][k]), h2, s3);
        }
      }
      a0 += (float)s0.x + (float)s0.y;
      a1 += (float)s1.x + (float)s1.y;
      a2 += (float)s2.x + (float)s2.y;
      a3 += (float)s3.x + (float)s3.y;
    }
    // LDS-weight section: 32 pairs
    {
      half2_t s0 = {(_Float16)0.f,(_Float16)0.f}, s1 = s0, s2 = s0, s3 = s0;
      #pragma unroll
      for (int k8=0; k8<8; ++k8){
        const uint4 hh = *(const uint4*)(hr + KREG + k8*4);
        #pragma unroll
        for (int p=0; p<4; ++p){
          const uint4 w = wlds[(k8*4+p)*256 + j];
          const half2_t h2 = __builtin_bit_cast(half2_t, (&hh.x)[p]);
          s0 = __builtin_elementwise_fma(__builtin_bit_cast(half2_t, w.x), h2, s0);
          s1 = __builtin_elementwise_fma(__builtin_bit_cast(half2_t, w.y), h2, s1);
          s2 = __builtin_elementwise_fma(__builtin_bit_cast(half2_t, w.z), h2, s2);
          s3 = __builtin_elementwise_fma(__builtin_bit_cast(half2_t, w.w), h2, s3);
        }
      }
      a0 += (float)s0.x + (float)s0.y;
      a1 += (float)s1.x + (float)s1.y;
      a2 += (float)s2.x + (float)s2.y;
      a3 += (float)s3.x + (float)s3.y;
    }

    a0 += (float)x0; a1 += (float)x1; a2 += (float)x2; a3 += (float)x3;
    const float gi = sigf(a0);
    const float gf = sigf(a1);
    const float gg = tanh_f(a2);
    const float go = sigf(a3);
    c = gf*c + gi*gg;
    const float h = go * tanh_f(c);

    const half_t hh16 = (half_t)h;
    ((unsigned short*)(hbuf + (t&1)*128))[j] = __builtin_bit_cast(unsigned short, hh16);
    if (wr32) h32[(base + t)*H_N + j] = h;
    else      h16[(base + t)*H_N + j] = hh16;
    if (t == S_N-1){ hT[b*H_N + j] = h; cT[b*H_N + j] = c; }
    __syncthreads();   // covers W(t)->R(t+1) RAW and R(t)->W(t+1) WAR (different buffers)
  }
}

extern "C" void kernel_launch(void* const* d_in, const int* in_sizes, int n_in,
                              void* d_out, int out_size, void* d_ws, size_t ws_size,
                              hipStream_t stream)
{
  const float* x   = (const float*)d_in[0];
  const float* Wih = (const float*)d_in[1];
  const float* bih = (const float*)d_in[2];
  const float* Whh = (const float*)d_in[3];
  const float* bhh = (const float*)d_in[4];
  float* out = (float*)d_out;

  char* ws = (char*)d_ws;
  half_t* A0   = (half_t*)(ws + WS_A0);    // layer-0 fp16 input; reused as h0 sequence
  half_t* XP   = (half_t*)(ws + WS_XP);
  half_t* Wi16 = (half_t*)(ws + WS_WI);
  half_t* Wh16 = (half_t*)(ws + WS_WH);
  float*  bsum = (float*)(ws + WS_BSUM);

  cvt_f32_f16<<<dim3(M_N*H_N/256), dim3(256), 0, stream>>>(x, A0, M_N*H_N);
  cvt_f32_f16<<<dim3(L_N*G_N*H_N/256), dim3(256), 0, stream>>>(Wih, Wi16, L_N*G_N*H_N);
  cvt_f32_f16<<<dim3(L_N*G_N*H_N/256), dim3(256), 0, stream>>>(Whh, Wh16, L_N*G_N*H_N);
  make_bsum<<<dim3(L_N*G_N/256), dim3(256), 0, stream>>>(bih, bhh, bsum, L_N*G_N);

  float* hT = out + (size_t)M_N*H_N;       // hs [2][32][256]
  float* cT = hT + (size_t)L_N*B_N*H_N;    // cs [2][32][256]

  // ---- layer 0
  gemm_xp<<<dim3(M_N/64, G_N/64), dim3(256), 0, stream>>>(A0, Wi16, bsum, XP);
  lstm_rec<<<dim3(B_N), dim3(256), SMEM_BYTES, stream>>>(
      (const uint32_t*)Wh16, XP, A0 /*h0 seq overwrites dead A0*/, nullptr,
      hT, cT, 0);

  // ---- layer 1
  gemm_xp<<<dim3(M_N/64, G_N/64), dim3(256), 0, stream>>>(A0, Wi16 + (size_t)G_N*H_N, bsum + G_N, XP);
  lstm_rec<<<dim3(B_N), dim3(256), SMEM_BYTES, stream>>>(
      (const uint32_t*)(Wh16 + (size_t)G_N*H_N), XP, nullptr, out,
      hT + B_N*H_N, cT + B_N*H_N, 1);
}

// Round 2
// 6942.821 us; speedup vs baseline: 2.2715x; 2.2715x over previous
//
#include <hip/hip_runtime.h>
#include <cstdint>
#include <cstddef>

typedef _Float16 half_t;
typedef _Float16 half2_t __attribute__((ext_vector_type(2)));
typedef _Float16 half8_t __attribute__((ext_vector_type(8)));
typedef float   float4_t __attribute__((ext_vector_type(4)));

#define L_N 2
#define B_N 32
#define S_N 2048
#define H_N 256
#define G_N 1024            // 4H
#define M_N (B_N*S_N)       // 65536

// Recurrent kernel: 512 threads = 2 K-halves x 256 cells.
// Per thread: 4 gate rows x 64 pairs; KREG2 pairs in VGPRs, KLDS2 in LDS.
#define KREG2 48
#define KLDS2 16
#define SMEM_WT   (KLDS2*512*16)            // 131072 B weight tiles
#define SMEM_HB   (2*128*4)                 // double-buffered h pairs
#define SMEM_RED  (256*16)                  // float4 partial-sum reduce
#define SMEM_BYTES (SMEM_WT + SMEM_HB + SMEM_RED)

// ws layout (bytes)
#define WS_A0   0ull                 // fp16 [M][H]: layer-0 A; later reused as h0 sequence
#define WS_XP   33554432ull          // fp16 [M][G]: input projection (bias folded)
#define WS_WI   167772160ull         // fp16 [L][G][H]
#define WS_WH   168820736ull         // fp16 [L][G][H]
#define WS_BSUM 169869312ull         // f32 [L][G]  (b_ih + b_hh)

__global__ void cvt_f32_f16(const float* __restrict__ in, half_t* __restrict__ out, int n){
  int i = blockIdx.x*256 + threadIdx.x;
  if (i < n) out[i] = (half_t)in[i];
}

__global__ void make_bsum(const float* __restrict__ bi, const float* __restrict__ bh,
                          float* __restrict__ bs, int n){
  int i = blockIdx.x*256 + threadIdx.x;
  if (i < n) bs[i] = bi[i] + bh[i];
}

// XP[m,g] = sum_k A[m,k] * W[g,k] + bsum[g]; A:[M][256] fp16, W:[1024][256] fp16
__global__ __launch_bounds__(256) void gemm_xp(
    const half_t* __restrict__ A, const half_t* __restrict__ W,
    const float* __restrict__ bsum, half_t* __restrict__ XP)
{
  const int wave = threadIdx.x >> 6;
  const int lane = threadIdx.x & 63;
  const int l15 = lane & 15, quad = lane >> 4;
  const int m0 = blockIdx.x*64 + wave*16;
  const int n0 = blockIdx.y*64;
  float4_t acc[4] = {{0,0,0,0},{0,0,0,0},{0,0,0,0},{0,0,0,0}};
  const half_t* arow = A + (size_t)(m0 + l15)*H_N + quad*8;
  const half_t* brow[4];
  #pragma unroll
  for (int nt=0; nt<4; ++nt)
    brow[nt] = W + (size_t)(n0 + nt*16 + l15)*H_N + quad*8;
  #pragma unroll
  for (int k0=0; k0<H_N; k0+=32){
    half8_t af = *(const half8_t*)(arow + k0);
    #pragma unroll
    for (int nt=0; nt<4; ++nt){
      half8_t bf = *(const half8_t*)(brow[nt] + k0);
      acc[nt] = __builtin_amdgcn_mfma_f32_16x16x32_f16(af, bf, acc[nt], 0, 0, 0);
    }
  }
  #pragma unroll
  for (int nt=0; nt<4; ++nt){
    const int col = n0 + nt*16 + l15;
    const float bs = bsum[col];
    #pragma unroll
    for (int r=0; r<4; ++r){
      XP[(size_t)(m0 + quad*4 + r)*G_N + col] = (half_t)(acc[nt][r] + bs);
    }
  }
}

__device__ __forceinline__ float sigf(float x){ return 1.f/(1.f + __expf(-x)); }
__device__ __forceinline__ float tanh_f(float x){ return 1.f - 2.f/(__expf(2.f*x) + 1.f); }

// Persistent per-batch-chain LSTM recurrence. 1 block = 1 chain = 1 CU.
// 512 threads: tid = (kh<<8)|j. Thread owns gates {j,j+256,j+512,j+768} over
// K-pairs [kh*64, kh*64+64). v_dot2_f32_f16 accumulate (f32). Partial sums
// from kh=1 reduced via LDS float4; kh=0 applies xp+nonlinearity, owns c_j.
__global__ __launch_bounds__(512,2) void lstm_rec(
    const uint32_t* __restrict__ Wp,   // fp16-pair view of Wh [1024][128]
    const half_t*  __restrict__ xp,    // [M][1024], biases folded
    half_t* __restrict__ h16,          // layer-0 h sequence out (fp16)
    float*  __restrict__ h32,          // layer-1 h sequence out (fp32, = d_out x)
    float*  __restrict__ hT, float* __restrict__ cT, int wr32)
{
  extern __shared__ unsigned char smem[];
  uint4*    wlds = (uint4*)smem;                     // [KLDS2][512]
  uint32_t* hbuf = (uint32_t*)(smem + SMEM_WT);      // [2][128] h pairs
  float4*   red  = (float4*)(smem + SMEM_WT + SMEM_HB); // [256]
  const int tid = threadIdx.x;
  const int j  = tid & 255;
  const int kh = tid >> 8;
  const int b  = blockIdx.x;

  // --- VGPR-resident weights: pairs kh*64 + [0, KREG2) of each of 4 gate rows
  uint32_t wreg[4][KREG2];
  #pragma unroll
  for (int q=0; q<4; ++q){
    const uint32_t* wp = Wp + (size_t)(q*256 + j)*128 + kh*64;
    #pragma unroll
    for (int k=0; k<KREG2; ++k) wreg[q][k] = wp[k];
  }
  // --- LDS-resident weights: pairs kh*64 + KREG2 + [0, KLDS2), 4 gates packed per uint4
  {
    const uint32_t* w0 = Wp + (size_t)(  0 + j)*128 + kh*64 + KREG2;
    const uint32_t* w1 = Wp + (size_t)(256 + j)*128 + kh*64 + KREG2;
    const uint32_t* w2 = Wp + (size_t)(512 + j)*128 + kh*64 + KREG2;
    const uint32_t* w3 = Wp + (size_t)(768 + j)*128 + kh*64 + KREG2;
    #pragma unroll
    for (int k=0; k<KLDS2; ++k){
      uint4 v; v.x = w0[k]; v.y = w1[k]; v.z = w2[k]; v.w = w3[k];
      wlds[k*512 + tid] = v;
    }
  }
  if (tid < 128) hbuf[128 + tid] = 0u;   // initial h (read buffer of t=0) = 0
  float c = 0.f;
  __syncthreads();

  const size_t base = (size_t)b * S_N;
  for (int t=0; t<S_N; ++t){
    const uint32_t* hr = hbuf + ((t+1)&1)*128 + kh*64;  // this half's 64 prev-h pairs
    float a0=0.f, a1=0.f, a2=0.f, a3=0.f;

    half_t x0=(half_t)0.f, x1=x0, x2=x0, x3=x0;
    if (!kh){
      const half_t* xr = xp + (base + t)*G_N + j;
      x0 = xr[0]; x1 = xr[256]; x2 = xr[512]; x3 = xr[768];
    }

    // VGPR-weight section: KREG2 pairs, f32 dot2 accumulate
    #pragma unroll
    for (int k8=0; k8<KREG2/4; ++k8){
      const uint4 hh = *(const uint4*)(hr + k8*4);
      #pragma unroll
      for (int p=0; p<4; ++p){
        const int k = k8*4 + p;
        const half2_t h2 = __builtin_bit_cast(half2_t, (&hh.x)[p]);
        a0 = __builtin_amdgcn_fdot2(__builtin_bit_cast(half2_t, wreg[0][k]), h2, a0, false);
        a1 = __builtin_amdgcn_fdot2(__builtin_bit_cast(half2_t, wreg[1][k]), h2, a1, false);
        a2 = __builtin_amdgcn_fdot2(__builtin_bit_cast(half2_t, wreg[2][k]), h2, a2, false);
        a3 = __builtin_amdgcn_fdot2(__builtin_bit_cast(half2_t, wreg[3][k]), h2, a3, false);
      }
    }
    // LDS-weight section: KLDS2 pairs
    #pragma unroll
    for (int k8=0; k8<KLDS2/4; ++k8){
      const uint4 hh = *(const uint4*)(hr + KREG2 + k8*4);
      #pragma unroll
      for (int p=0; p<4; ++p){
        const uint4 w = wlds[(k8*4+p)*512 + tid];
        const half2_t h2 = __builtin_bit_cast(half2_t, (&hh.x)[p]);
        a0 = __builtin_amdgcn_fdot2(__builtin_bit_cast(half2_t, w.x), h2, a0, false);
        a1 = __builtin_amdgcn_fdot2(__builtin_bit_cast(half2_t, w.y), h2, a1, false);
        a2 = __builtin_amdgcn_fdot2(__builtin_bit_cast(half2_t, w.z), h2, a2, false);
        a3 = __builtin_amdgcn_fdot2(__builtin_bit_cast(half2_t, w.w), h2, a3, false);
      }
    }

    if (kh){ float4 r; r.x=a0; r.y=a1; r.z=a2; r.w=a3; red[j] = r; }
    __syncthreads();
    if (!kh){
      const float4 r = red[j];
      a0 += r.x + (float)x0;
      a1 += r.y + (float)x1;
      a2 += r.z + (float)x2;
      a3 += r.w + (float)x3;
      const float gi = sigf(a0);
      const float gf = sigf(a1);
      const float gg = tanh_f(a2);
      const float go = sigf(a3);
      c = gf*c + gi*gg;
      const float h = go * tanh_f(c);

      const half_t hh16 = (half_t)h;
      ((unsigned short*)(hbuf + (t&1)*128))[j] = __builtin_bit_cast(unsigned short, hh16);
      if (wr32) h32[(base + t)*H_N + j] = h;
      else      h16[(base + t)*H_N + j] = hh16;
      if (t == S_N-1){ hT[b*H_N + j] = h; cT[b*H_N + j] = c; }
    }
    __syncthreads();   // h-write visible; WAR on red + h buffers
  }
}

extern "C" void kernel_launch(void* const* d_in, const int* in_sizes, int n_in,
                              void* d_out, int out_size, void* d_ws, size_t ws_size,
                              hipStream_t stream)
{
  const float* x   = (const float*)d_in[0];
  const float* Wih = (const float*)d_in[1];
  const float* bih = (const float*)d_in[2];
  const float* Whh = (const float*)d_in[3];
  const float* bhh = (const float*)d_in[4];
  float* out = (float*)d_out;

  char* ws = (char*)d_ws;
  half_t* A0   = (half_t*)(ws + WS_A0);    // layer-0 fp16 input; reused as h0 sequence
  half_t* XP   = (half_t*)(ws + WS_XP);
  half_t* Wi16 = (half_t*)(ws + WS_WI);
  half_t* Wh16 = (half_t*)(ws + WS_WH);
  float*  bsum = (float*)(ws + WS_BSUM);

  cvt_f32_f16<<<dim3(M_N*H_N/256), dim3(256), 0, stream>>>(x, A0, M_N*H_N);
  cvt_f32_f16<<<dim3(L_N*G_N*H_N/256), dim3(256), 0, stream>>>(Wih, Wi16, L_N*G_N*H_N);
  cvt_f32_f16<<<dim3(L_N*G_N*H_N/256), dim3(256), 0, stream>>>(Whh, Wh16, L_N*G_N*H_N);
  make_bsum<<<dim3(L_N*G_N/256), dim3(256), 0, stream>>>(bih, bhh, bsum, L_N*G_N);

  float* hT = out + (size_t)M_N*H_N;       // hs [2][32][256]
  float* cT = hT + (size_t)L_N*B_N*H_N;    // cs [2][32][256]

  // ---- layer 0
  gemm_xp<<<dim3(M_N/64, G_N/64), dim3(256), 0, stream>>>(A0, Wi16, bsum, XP);
  lstm_rec<<<dim3(B_N), dim3(512), SMEM_BYTES, stream>>>(
      (const uint32_t*)Wh16, XP, A0 /*h0 seq overwrites dead A0*/, nullptr,
      hT, cT, 0);

  // ---- layer 1
  gemm_xp<<<dim3(M_N/64, G_N/64), dim3(256), 0, stream>>>(A0, Wi16 + (size_t)G_N*H_N, bsum + G_N, XP);
  lstm_rec<<<dim3(B_N), dim3(512), SMEM_BYTES, stream>>>(
      (const uint32_t*)(Wh16 + (size_t)G_N*H_N), XP, nullptr, out,
      hT + B_N*H_N, cT + B_N*H_N, 1);
}